// Round 2
// baseline (1220.148 us; speedup 1.0000x reference)
//
#include <hip/hip_runtime.h>
#include <math.h>

#define TSEQ 4096
#define NQH 16
#define NKVH 8
#define HD 128
#define WINSZ 1024
#define QT 128      // q rows per block (4 waves x 2 stripes x 16)
#define KT 64       // kv rows per tile

#define KSTR 136    // sK row stride in halves (128 + 8 pad)
#define VSTR 72     // sV row stride in halves (64 + 8 pad)
#define PSTR 72     // sP row stride in halves

typedef _Float16 h8 __attribute__((ext_vector_type(8)));
typedef _Float16 h4 __attribute__((ext_vector_type(4)));
typedef float    f4 __attribute__((ext_vector_type(4)));

// 16-lane (DPP row) reductions on the VALU pipe — no ds_swizzle latency.
#define DPP_FMAX(v, ctrl)                                                        \
  { int _t = __builtin_amdgcn_update_dpp(0, __builtin_bit_cast(int, v), ctrl,    \
                                         0xf, 0xf, true);                        \
    v = fmaxf(v, __builtin_bit_cast(float, _t)); }
#define DPP_FADD(v, ctrl)                                                        \
  { int _t = __builtin_amdgcn_update_dpp(0, __builtin_bit_cast(int, v), ctrl,    \
                                         0xf, 0xf, true);                        \
    v = v + __builtin_bit_cast(float, _t); }

// Flash sliding-window attention, GQA 16q/8kv, d=128, window=1024 (incl. self).
// MFMA 16x16x32 f16. C/D: col=lane&15, row=quad*4+reg. A: A[m=ln][k=quad*8+j+32*ks].
__global__ __launch_bounds__(256, 3)
void fa_swa_kernel(const float* __restrict__ Qg, const float* __restrict__ Kg,
                   const float* __restrict__ Vg, float* __restrict__ Og) {
  __shared__ _Float16 sK[KT * KSTR];        // [s][dd] fp16        17408 B
  __shared__ _Float16 sV[HD * VSTR];        // [dd][s] fp16 (T)    18432 B
  __shared__ _Float16 sP[4][16 * PSTR];     // per-wave P buffer    9216 B -> 44 KB total

  const int tid  = threadIdx.x;
  const int w    = tid >> 6;
  const int lane = tid & 63;
  const int quad = lane >> 4;
  const int ln   = lane & 15;

  const int qt = blockIdx.x;
  const int h  = blockIdx.y;
  const int bz = blockIdx.z;
  const int hk = h >> 1;
  const int q0 = qt * QT;

  // ---- Q fragments in registers (A-layout), fp32 -> fp16 ----
  h8 qf[2][4];
  #pragma unroll
  for (int r = 0; r < 2; ++r) {
    const int qg = q0 + w * 32 + r * 16 + ln;
    const float* qp = Qg + ((size_t)((size_t)bz * TSEQ + qg) * NQH + h) * HD + quad * 8;
    #pragma unroll
    for (int ks = 0; ks < 4; ++ks) {
      f4 a = *(const f4*)(qp + ks * 32);
      f4 b = *(const f4*)(qp + ks * 32 + 4);
      h8 qv;
      qv[0] = (_Float16)a[0]; qv[1] = (_Float16)a[1];
      qv[2] = (_Float16)a[2]; qv[3] = (_Float16)a[3];
      qv[4] = (_Float16)b[0]; qv[5] = (_Float16)b[1];
      qv[6] = (_Float16)b[2]; qv[7] = (_Float16)b[3];
      qf[r][ks] = qv;
    }
  }

  f4 Oacc[2][8];
  #pragma unroll
  for (int r = 0; r < 2; ++r)
    #pragma unroll
    for (int c = 0; c < 8; ++c)
      Oacc[r][c] = (f4){0.f, 0.f, 0.f, 0.f};

  float mrow[8], lrow[8];
  #pragma unroll
  for (int i = 0; i < 8; ++i) { mrow[i] = -INFINITY; lrow[i] = 0.f; }

  int s_begin = q0 - WINSZ; if (s_begin < 0) s_begin = 0;   // multiple of 64
  const int s_end = q0 + QT;

  const float* kbase = Kg + ((size_t)((size_t)bz * TSEQ) * NKVH + hk) * HD;
  const float* vbase = Vg + ((size_t)((size_t)bz * TSEQ) * NKVH + hk) * HD;

  for (int s0 = s_begin; s0 < s_end; s0 += KT) {
    __syncthreads();   // protect sK/sV from previous iteration's readers

    // ---- stage K tile: sK[s][dd], coalesced f4 loads, packed cvt, b64 LDS writes ----
    {
      const float* kp = kbase + (size_t)s0 * (NKVH * HD);
      #pragma unroll
      for (int i = 0; i < 8; ++i) {
        int e   = tid + 256 * i;     // float4 index within 64x128 tile
        int row = e >> 5;
        int c4  = (e & 31) * 4;
        f4 x = *(const f4*)(kp + (size_t)row * (NKVH * HD) + c4);
        h4 hv;
        hv[0] = (_Float16)x[0]; hv[1] = (_Float16)x[1];
        hv[2] = (_Float16)x[2]; hv[3] = (_Float16)x[3];
        *(h4*)(&sK[row * KSTR + c4]) = hv;
      }
    }
    // ---- stage V tile transposed: sV[dd][s] ----
    {
      const int srow = tid & 63;
      const int dd0  = (tid >> 6) * 32;
      const float* vp = vbase + (size_t)(s0 + srow) * (NKVH * HD) + dd0;
      #pragma unroll
      for (int f = 0; f < 8; ++f) {
        f4 x = *(const f4*)(vp + f * 4);
        #pragma unroll
        for (int c = 0; c < 4; ++c)
          sV[(dd0 + f * 4 + c) * VSTR + srow] = (_Float16)x[c];
      }
    }
    __syncthreads();

    // ---- per-stripe activity: dq = stripe_base - s0; active iff some (q,s) in window ----
    const int dq0 = q0 + w * 32 - s0;
    bool act[2];
    f4 S[2][4];
    #pragma unroll
    for (int r = 0; r < 2; ++r) {
      const int dq = dq0 + r * 16;
      act[r] = (dq >= 0) && (dq <= 1072);
      if (act[r]) {
        // S = Q K^T (16 x 64)
        #pragma unroll
        for (int ct = 0; ct < 4; ++ct) {
          f4 acc = (f4){0.f, 0.f, 0.f, 0.f};
          #pragma unroll
          for (int ks = 0; ks < 4; ++ks) {
            h8 kb = *(const h8*)(&sK[(ct * 16 + ln) * KSTR + quad * 8 + ks * 32]);
            acc = __builtin_amdgcn_mfma_f32_16x16x32_f16(qf[r][ks], kb, acc, 0, 0, 0);
          }
          S[r][ct] = acc;
        }
        // mask only boundary tiles (uniform branch); interior tiles skip entirely
        if (dq < 64 || dq > 1008) {
          const int e = dq + quad * 4 - ln;
          #pragma unroll
          for (int ct = 0; ct < 4; ++ct) {
            const int base = e - ct * 16;
            #pragma unroll
            for (int g = 0; g < 4; ++g)
              if ((unsigned)(base + g) > 1023u) S[r][ct][g] = -INFINITY;
          }
        }
      }
    }

    // ---- online softmax: 8 interleaved DPP row-reductions (VALU pipe) ----
    float red[8];
    #pragma unroll
    for (int r = 0; r < 2; ++r)
      #pragma unroll
      for (int g = 0; g < 4; ++g) {
        float m = -INFINITY;
        if (act[r]) {
          #pragma unroll
          for (int ct = 0; ct < 4; ++ct) m = fmaxf(m, S[r][ct][g]);
        }
        red[r * 4 + g] = m;
      }
    #pragma unroll
    for (int i = 0; i < 8; ++i) DPP_FMAX(red[i], 0x121);
    #pragma unroll
    for (int i = 0; i < 8; ++i) DPP_FMAX(red[i], 0x122);
    #pragma unroll
    for (int i = 0; i < 8; ++i) DPP_FMAX(red[i], 0x124);
    #pragma unroll
    for (int i = 0; i < 8; ++i) DPP_FMAX(red[i], 0x128);

    float mn[8], al[8], ps[8];
    #pragma unroll
    for (int i = 0; i < 8; ++i) {
      const float m = fmaxf(mrow[i], red[i]);
      mn[i] = m;
      al[i] = (m == -INFINITY) ? 1.f : __expf(mrow[i] - m);
      mrow[i] = m;
      ps[i] = 0.f;
    }
    #pragma unroll
    for (int r = 0; r < 2; ++r)
      if (act[r]) {
        #pragma unroll
        for (int ct = 0; ct < 4; ++ct)
          #pragma unroll
          for (int g = 0; g < 4; ++g) {
            const float m = mn[r * 4 + g];
            float p = __expf(S[r][ct][g] - m);     // exp(-inf - finite) = 0
            p = (m == -INFINITY) ? 0.f : p;        // fully-masked row guard
            S[r][ct][g] = p;
            ps[r * 4 + g] += p;
          }
      }
    #pragma unroll
    for (int i = 0; i < 8; ++i) DPP_FADD(ps[i], 0x121);
    #pragma unroll
    for (int i = 0; i < 8; ++i) DPP_FADD(ps[i], 0x122);
    #pragma unroll
    for (int i = 0; i < 8; ++i) DPP_FADD(ps[i], 0x124);
    #pragma unroll
    for (int i = 0; i < 8; ++i) DPP_FADD(ps[i], 0x128);
    #pragma unroll
    for (int i = 0; i < 8; ++i) lrow[i] = lrow[i] * al[i] + ps[i];

    // ---- rescale O, then P->LDS->A-layout, PV MFMA (single per-wave sP) ----
    #pragma unroll
    for (int r = 0; r < 2; ++r)
      if (act[r]) {
        #pragma unroll
        for (int ct = 0; ct < 8; ++ct)
          #pragma unroll
          for (int g = 0; g < 4; ++g)
            Oacc[r][ct][g] *= al[r * 4 + g];

        __asm__ volatile("s_waitcnt lgkmcnt(0)" ::: "memory");  // prior pa reads retired
        #pragma unroll
        for (int ct = 0; ct < 4; ++ct)
          #pragma unroll
          for (int g = 0; g < 4; ++g)
            sP[w][(quad * 4 + g) * PSTR + ct * 16 + ln] = (_Float16)S[r][ct][g];
        __asm__ volatile("s_waitcnt lgkmcnt(0)" ::: "memory");  // wave-private RAW

        #pragma unroll
        for (int ks = 0; ks < 2; ++ks) {
          h8 pa = *(const h8*)(&sP[w][ln * PSTR + quad * 8 + ks * 32]);
          #pragma unroll
          for (int ct = 0; ct < 8; ++ct) {
            h8 vb = *(const h8*)(&sV[(ct * 16 + ln) * VSTR + quad * 8 + ks * 32]);
            Oacc[r][ct] = __builtin_amdgcn_mfma_f32_16x16x32_f16(pa, vb, Oacc[r][ct], 0, 0, 0);
          }
        }
      }
  }

  // ---- epilogue: O / l, fp32 stores ----
  #pragma unroll
  for (int r = 0; r < 2; ++r) {
    const int qrb = q0 + w * 32 + r * 16 + quad * 4;
    float inv[4];
    #pragma unroll
    for (int g = 0; g < 4; ++g) inv[g] = 1.f / lrow[r * 4 + g];
    #pragma unroll
    for (int ct = 0; ct < 8; ++ct)
      #pragma unroll
      for (int g = 0; g < 4; ++g)
        Og[((size_t)((size_t)bz * TSEQ + (qrb + g)) * NQH + h) * HD + ct * 16 + ln] =
            Oacc[r][ct][g] * inv[g];
  }
}

extern "C" void kernel_launch(void* const* d_in, const int* in_sizes, int n_in,
                              void* d_out, int out_size, void* d_ws, size_t ws_size,
                              hipStream_t stream) {
  const float* Q = (const float*)d_in[0];
  const float* K = (const float*)d_in[1];
  const float* V = (const float*)d_in[2];
  float* O = (float*)d_out;
  const int batch = in_sizes[0] / (TSEQ * NQH * HD);   // 4
  dim3 grid(TSEQ / QT, NQH, batch);
  fa_swa_kernel<<<grid, 256, 0, stream>>>(Q, K, V, O);
}

// Round 3
// 623.723 us; speedup vs baseline: 1.9562x; 1.9562x over previous
//
#include <hip/hip_runtime.h>
#include <math.h>

#define TSEQ 4096
#define NQH 16
#define NKVH 8
#define HD 128
#define WINSZ 1024
#define QT 128      // q rows per block (4 waves x 2 stripes x 16)
#define KT 64       // kv rows per tile

#define KSTR 136    // sK row stride in halves (128 + 8 pad)
#define VSTR 72     // sV row stride in halves (64 + 8 pad)
#define PSTR 72     // sP row stride in halves

typedef _Float16 h8 __attribute__((ext_vector_type(8)));
typedef _Float16 h4 __attribute__((ext_vector_type(4)));
typedef float    f4 __attribute__((ext_vector_type(4)));

// 16-lane (DPP row) reductions on the VALU pipe — no ds_swizzle latency.
#define DPP_FMAX(v, ctrl)                                                        \
  { int _t = __builtin_amdgcn_update_dpp(0, __builtin_bit_cast(int, v), ctrl,    \
                                         0xf, 0xf, true);                        \
    v = fmaxf(v, __builtin_bit_cast(float, _t)); }
#define DPP_FADD(v, ctrl)                                                        \
  { int _t = __builtin_amdgcn_update_dpp(0, __builtin_bit_cast(int, v), ctrl,    \
                                         0xf, 0xf, true);                        \
    v = v + __builtin_bit_cast(float, _t); }

// Flash sliding-window attention, GQA 16q/8kv, d=128, window=1024 (incl. self).
// MFMA 16x16x32 f16. C/D: col=lane&15, row=quad*4+reg. A: A[m=ln][k=quad*8+j+32*ks].
// NOTE: __launch_bounds__(256,2) — (256,3) forces VGPR cap 84 -> ~1.1 GB spill
// traffic per launch (R2: WRITE_SIZE 131 MB -> 1.255 GB, dur 2x). Do not raise.
__global__ __launch_bounds__(256, 2)
void fa_swa_kernel(const float* __restrict__ Qg, const float* __restrict__ Kg,
                   const float* __restrict__ Vg, float* __restrict__ Og) {
  __shared__ _Float16 sK[KT * KSTR];        // [s][dd] fp16        17408 B
  __shared__ _Float16 sV[HD * VSTR];        // [dd][s] fp16 (T)    18432 B
  __shared__ _Float16 sP[4][16 * PSTR];     // per-wave P buffer    9216 B -> 44 KB

  const int tid  = threadIdx.x;
  const int w    = tid >> 6;
  const int lane = tid & 63;
  const int quad = lane >> 4;
  const int ln   = lane & 15;

  const int qt = blockIdx.x;
  const int h  = blockIdx.y;
  const int bz = blockIdx.z;
  const int hk = h >> 1;
  const int q0 = qt * QT;

  // ---- Q fragments in registers (A-layout), fp32 -> fp16 ----
  h8 qf[2][4];
  #pragma unroll
  for (int r = 0; r < 2; ++r) {
    const int qg = q0 + w * 32 + r * 16 + ln;
    const float* qp = Qg + ((size_t)((size_t)bz * TSEQ + qg) * NQH + h) * HD + quad * 8;
    #pragma unroll
    for (int ks = 0; ks < 4; ++ks) {
      f4 a = *(const f4*)(qp + ks * 32);
      f4 b = *(const f4*)(qp + ks * 32 + 4);
      h8 qv;
      qv[0] = (_Float16)a[0]; qv[1] = (_Float16)a[1];
      qv[2] = (_Float16)a[2]; qv[3] = (_Float16)a[3];
      qv[4] = (_Float16)b[0]; qv[5] = (_Float16)b[1];
      qv[6] = (_Float16)b[2]; qv[7] = (_Float16)b[3];
      qf[r][ks] = qv;
    }
  }

  f4 Oacc[2][8];
  #pragma unroll
  for (int r = 0; r < 2; ++r)
    #pragma unroll
    for (int c = 0; c < 8; ++c)
      Oacc[r][c] = (f4){0.f, 0.f, 0.f, 0.f};

  float mrow[8], lrow[8];
  #pragma unroll
  for (int i = 0; i < 8; ++i) { mrow[i] = -INFINITY; lrow[i] = 0.f; }

  int s_begin = q0 - WINSZ; if (s_begin < 0) s_begin = 0;   // multiple of 64
  const int s_end = q0 + QT;

  const float* kbase = Kg + ((size_t)((size_t)bz * TSEQ) * NKVH + hk) * HD;
  const float* vbase = Vg + ((size_t)((size_t)bz * TSEQ) * NKVH + hk) * HD;

  for (int s0 = s_begin; s0 < s_end; s0 += KT) {
    __syncthreads();   // protect sK/sV from previous iteration's readers

    // ---- stage K tile: sK[s][dd], coalesced f4 loads ----
    {
      const float* kp = kbase + (size_t)s0 * (NKVH * HD);
      #pragma unroll
      for (int i = 0; i < 8; ++i) {
        int e   = tid + 256 * i;     // float4 index within 64x128 tile
        int row = e >> 5;
        int c4  = (e & 31) * 4;
        f4 x = *(const f4*)(kp + (size_t)row * (NKVH * HD) + c4);
        h4 hv;
        hv[0] = (_Float16)x[0]; hv[1] = (_Float16)x[1];
        hv[2] = (_Float16)x[2]; hv[3] = (_Float16)x[3];
        *(h4*)(&sK[row * KSTR + c4]) = hv;
      }
    }
    // ---- stage V tile transposed: sV[dd][s] ----
    {
      const int srow = tid & 63;
      const int dd0  = (tid >> 6) * 32;
      const float* vp = vbase + (size_t)(s0 + srow) * (NKVH * HD) + dd0;
      #pragma unroll
      for (int f = 0; f < 8; ++f) {
        f4 x = *(const f4*)(vp + f * 4);
        #pragma unroll
        for (int c = 0; c < 4; ++c)
          sV[(dd0 + f * 4 + c) * VSTR + srow] = (_Float16)x[c];
      }
    }
    __syncthreads();

    // ---- per-stripe activity: dq = stripe_base - s0 ----
    const int dq0 = q0 + w * 32 - s0;
    bool act[2];
    f4 S[2][4];
    #pragma unroll
    for (int r = 0; r < 2; ++r) {
      const int dq = dq0 + r * 16;
      act[r] = (dq >= 0) && (dq <= 1072);
      if (act[r]) {
        // S = Q K^T (16 x 64)
        #pragma unroll
        for (int ct = 0; ct < 4; ++ct) {
          f4 acc = (f4){0.f, 0.f, 0.f, 0.f};
          #pragma unroll
          for (int ks = 0; ks < 4; ++ks) {
            h8 kb = *(const h8*)(&sK[(ct * 16 + ln) * KSTR + quad * 8 + ks * 32]);
            acc = __builtin_amdgcn_mfma_f32_16x16x32_f16(qf[r][ks], kb, acc, 0, 0, 0);
          }
          S[r][ct] = acc;
        }
        // mask only boundary tiles (uniform branch); interior tiles skip entirely
        if (dq < 64 || dq > 1008) {
          const int e = dq + quad * 4 - ln;
          #pragma unroll
          for (int ct = 0; ct < 4; ++ct) {
            const int base = e - ct * 16;
            #pragma unroll
            for (int g = 0; g < 4; ++g)
              if ((unsigned)(base + g) > 1023u) S[r][ct][g] = -INFINITY;
          }
        }
      }
    }

    // ---- online softmax: 8 interleaved DPP row-reductions (VALU pipe) ----
    float red[8];
    #pragma unroll
    for (int r = 0; r < 2; ++r)
      #pragma unroll
      for (int g = 0; g < 4; ++g) {
        float m = -INFINITY;
        if (act[r]) {
          #pragma unroll
          for (int ct = 0; ct < 4; ++ct) m = fmaxf(m, S[r][ct][g]);
        }
        red[r * 4 + g] = m;
      }
    #pragma unroll
    for (int i = 0; i < 8; ++i) DPP_FMAX(red[i], 0x121);
    #pragma unroll
    for (int i = 0; i < 8; ++i) DPP_FMAX(red[i], 0x122);
    #pragma unroll
    for (int i = 0; i < 8; ++i) DPP_FMAX(red[i], 0x124);
    #pragma unroll
    for (int i = 0; i < 8; ++i) DPP_FMAX(red[i], 0x128);

    float mn[8], al[8], ps[8];
    #pragma unroll
    for (int i = 0; i < 8; ++i) {
      const float m = fmaxf(mrow[i], red[i]);
      mn[i] = m;
      al[i] = (m == -INFINITY) ? 1.f : __expf(mrow[i] - m);
      mrow[i] = m;
      ps[i] = 0.f;
    }
    #pragma unroll
    for (int r = 0; r < 2; ++r)
      if (act[r]) {
        #pragma unroll
        for (int ct = 0; ct < 4; ++ct)
          #pragma unroll
          for (int g = 0; g < 4; ++g) {
            const float m = mn[r * 4 + g];
            float p = __expf(S[r][ct][g] - m);     // exp(-inf - finite) = 0
            p = (m == -INFINITY) ? 0.f : p;        // fully-masked row guard
            S[r][ct][g] = p;
            ps[r * 4 + g] += p;
          }
      }
    #pragma unroll
    for (int i = 0; i < 8; ++i) DPP_FADD(ps[i], 0x121);
    #pragma unroll
    for (int i = 0; i < 8; ++i) DPP_FADD(ps[i], 0x122);
    #pragma unroll
    for (int i = 0; i < 8; ++i) DPP_FADD(ps[i], 0x124);
    #pragma unroll
    for (int i = 0; i < 8; ++i) DPP_FADD(ps[i], 0x128);
    #pragma unroll
    for (int i = 0; i < 8; ++i) lrow[i] = lrow[i] * al[i] + ps[i];

    // ---- rescale O, then P->LDS->A-layout, PV MFMA (single per-wave sP) ----
    #pragma unroll
    for (int r = 0; r < 2; ++r)
      if (act[r]) {
        #pragma unroll
        for (int ct = 0; ct < 8; ++ct)
          #pragma unroll
          for (int g = 0; g < 4; ++g)
            Oacc[r][ct][g] *= al[r * 4 + g];

        __asm__ volatile("s_waitcnt lgkmcnt(0)" ::: "memory");  // prior pa reads retired
        #pragma unroll
        for (int ct = 0; ct < 4; ++ct)
          #pragma unroll
          for (int g = 0; g < 4; ++g)
            sP[w][(quad * 4 + g) * PSTR + ct * 16 + ln] = (_Float16)S[r][ct][g];
        __asm__ volatile("s_waitcnt lgkmcnt(0)" ::: "memory");  // wave-private RAW

        #pragma unroll
        for (int ks = 0; ks < 2; ++ks) {
          h8 pa = *(const h8*)(&sP[w][ln * PSTR + quad * 8 + ks * 32]);
          #pragma unroll
          for (int ct = 0; ct < 8; ++ct) {
            h8 vb = *(const h8*)(&sV[(ct * 16 + ln) * VSTR + quad * 8 + ks * 32]);
            Oacc[r][ct] = __builtin_amdgcn_mfma_f32_16x16x32_f16(pa, vb, Oacc[r][ct], 0, 0, 0);
          }
        }
      }
  }

  // ---- epilogue: O / l, fp32 stores ----
  #pragma unroll
  for (int r = 0; r < 2; ++r) {
    const int qrb = q0 + w * 32 + r * 16 + quad * 4;
    float inv[4];
    #pragma unroll
    for (int g = 0; g < 4; ++g) inv[g] = 1.f / lrow[r * 4 + g];
    #pragma unroll
    for (int ct = 0; ct < 8; ++ct)
      #pragma unroll
      for (int g = 0; g < 4; ++g)
        Og[((size_t)((size_t)bz * TSEQ + (qrb + g)) * NQH + h) * HD + ct * 16 + ln] =
            Oacc[r][ct][g] * inv[g];
  }
}

extern "C" void kernel_launch(void* const* d_in, const int* in_sizes, int n_in,
                              void* d_out, int out_size, void* d_ws, size_t ws_size,
                              hipStream_t stream) {
  const float* Q = (const float*)d_in[0];
  const float* K = (const float*)d_in[1];
  const float* V = (const float*)d_in[2];
  float* O = (float*)d_out;
  const int batch = in_sizes[0] / (TSEQ * NQH * HD);   // 4
  dim3 grid(TSEQ / QT, NQH, batch);
  fa_swa_kernel<<<grid, 256, 0, stream>>>(Q, K, V, O);
}